// Round 1
// baseline (13404.315 us; speedup 1.0000x reference)
//
#include <hip/hip_runtime.h>
#include <math.h>

// Trajectory2seq persistent-kernel round: the previous version spent ~7 ms of
// its 8.5 ms on 448 sequential kernel dispatches (launch+drain ~15us each)
// around ~1-2us phases. This round replaces the whole encoder/decoder loop
// with ONE cooperative persistent kernel (256 blocks x 512 threads = 1
// block/CU, 8 waves/CU -- same occupancy as before) and a flag/gen grid
// barrier (~1-2us) between phases. GEMM inner machinery (packed hi/lo bf16
// fragments, gemm_pipe, store_tile, role-split + LDS reduce) is ported
// verbatim to preserve numerics. fc gets a 2-wave K-split + 4-acc fp64 ILP
// (reassoc ~1e-13, harmless vs ~1e-3 argmax margin).

#define Bb   256
#define Tt   128
#define Hh   1024
#define Vv   64
#define LIN  457
#define ML   64
#define NKB_H  32   // K=1024 -> 32 k-blocks of 32
#define NKB_X  15   // K=480  -> 15 k-blocks
#define XST  496    // LDS x row stride (bank spread, 16B aligned)
#define NBLK 256    // persistent grid: 1 block per CU
#define NTHR 512    // 8 waves per block

typedef __bf16 bf16;
typedef __bf16 bf16x8 __attribute__((ext_vector_type(8)));
typedef float  f32x4  __attribute__((ext_vector_type(4)));

static __device__ __forceinline__ float bf2f(bf16 x) {
    unsigned short u = __builtin_bit_cast(unsigned short, x);
    unsigned int w = ((unsigned int)u) << 16;
    return __builtin_bit_cast(float, w);
}
static __device__ __forceinline__ unsigned short f2bfbits(float f) {
    unsigned int u = __builtin_bit_cast(unsigned int, f);
    u = u + 0x7FFFu + ((u >> 16) & 1u);   // RNE (finite only)
    return (unsigned short)(u >> 16);
}
static __device__ __forceinline__ bf16 f2bf(float f) {
    return __builtin_bit_cast(bf16, f2bfbits(f));
}

#define MFMA(a, b, c) __builtin_amdgcn_mfma_f32_16x16x32_bf16((a), (b), (c), 0, 0, 0)

// ---- one-time: fp32 W[N][K] -> packed hi/lo fragments ---------------------
__global__ __launch_bounds__(256) void pack_w_k(const float* __restrict__ src,
                                                bf16* __restrict__ hp,
                                                bf16* __restrict__ lp,
                                                int nkb, int src_ld, int kmax) {
    const int tid = blockIdx.x * 256 + threadIdx.x;
    const int lane = tid & 63;
    const int kb = (tid >> 6) % nkb;
    const int nt = tid / (64 * nkb);
    if (nt >= 64) return;
    const int row = nt * 16 + (lane & 15);
    const int k0 = kb * 32 + (lane >> 4) * 8;
    const float* s = src + (size_t)row * src_ld;
    bf16x8 h8, l8;
#pragma unroll
    for (int j = 0; j < 8; j++) {
        float v = (k0 + j < kmax) ? s[k0 + j] : 0.f;
        bf16 h = f2bf(v);
        h8[j] = h;
        l8[j] = f2bf(v - bf2f(h));
    }
    *(bf16x8*)(hp + (size_t)tid * 8) = h8;
    *(bf16x8*)(lp + (size_t)tid * 8) = l8;
}

// ---- pipelined 16x16 gemm over kb range (A and W packed-fragment) ---------
static __device__ __forceinline__ void gemm_pipe(const bf16* __restrict__ ah,
                                                 const bf16* __restrict__ al,
                                                 const bf16* __restrict__ wh,
                                                 const bf16* __restrict__ wl,
                                                 int kb0, int kb1, f32x4* acc) {
    if (kb0 >= kb1) return;
    bf16x8 cah = *(const bf16x8*)(ah + (size_t)kb0 * 512);
    bf16x8 cal = *(const bf16x8*)(al + (size_t)kb0 * 512);
    bf16x8 cwh = *(const bf16x8*)(wh + (size_t)kb0 * 512);
    bf16x8 cwl = *(const bf16x8*)(wl + (size_t)kb0 * 512);
    for (int kb = kb0; kb < kb1; kb++) {
        bf16x8 nah = cah, nal = cal, nwh = cwh, nwl = cwl;
        if (kb + 1 < kb1) {
            nah = *(const bf16x8*)(ah + (size_t)(kb + 1) * 512);
            nal = *(const bf16x8*)(al + (size_t)(kb + 1) * 512);
            nwh = *(const bf16x8*)(wh + (size_t)(kb + 1) * 512);
            nwl = *(const bf16x8*)(wl + (size_t)(kb + 1) * 512);
        }
        *acc = MFMA(cah, cwh, *acc);
        *acc = MFMA(cal, cwh, *acc);
        *acc = MFMA(cah, cwl, *acc);
        cah = nah; cal = nal; cwh = nwh; cwl = nwl;
    }
}

// packed-state store of 16x16 tile (hi/lo), tanh applied
static __device__ __forceinline__ void store_tile(f32x4 acc, int mt, int nt,
                                                  int lm, int quad,
                                                  bf16* __restrict__ ohi,
                                                  bf16* __restrict__ olo) {
    const int o32 = (nt & 1) * 16 + lm;
    const int kbs = nt >> 1;
    const size_t base = (((size_t)mt * 32 + kbs) * 64 + (o32 >> 3) * 16 + quad * 4) * 8
                        + (o32 & 7);
#pragma unroll
    for (int r = 0; r < 4; r++) {
        float h = tanhf(acc[r]);
        bf16 hb = f2bf(h);
        ohi[base + r * 8] = hb;
        olo[base + r * 8] = f2bf(h - bf2f(hb));
    }
}

// ------- one-time: EP[v][n] = emb[v] @ dec_Wih0^T + dec_b0 (fp64->fp32) ----
__global__ __launch_bounds__(256) void dec_pre_k(const float* __restrict__ emb,
                                                 const float* __restrict__ W,
                                                 const float* __restrict__ b,
                                                 float* __restrict__ EP) {
    const int n = blockIdx.x * 256 + threadIdx.x;
    const int v = blockIdx.y * 4;
    double acc[4];
    const double bv = (double)b[n];
    acc[0] = acc[1] = acc[2] = acc[3] = bv;
    const float* wr = W + (size_t)n * Hh;
#pragma unroll 4
    for (int k = 0; k < Hh; k++) {
        double wv = (double)wr[k];
        acc[0] = fma((double)emb[(size_t)(v + 0) * Hh + k], wv, acc[0]);
        acc[1] = fma((double)emb[(size_t)(v + 1) * Hh + k], wv, acc[1]);
        acc[2] = fma((double)emb[(size_t)(v + 2) * Hh + k], wv, acc[2]);
        acc[3] = fma((double)emb[(size_t)(v + 3) * Hh + k], wv, acc[3]);
    }
#pragma unroll
    for (int r = 0; r < 4; r++) EP[(size_t)(v + r) * Hh + n] = (float)acc[r];
}

// --------------------------- persistent kernel -----------------------------
struct Params {
    const float* x;
    const bf16 *w0h, *w0l;
    const bf16 *eU0h, *eU0l, *eW1h, *eW1l, *eU1h, *eU1l;
    const bf16 *dU0h, *dU0l, *dW1h, *dW1l, *dU1h, *dU1l;
    const float *eb0, *eb1, *db1;
    const float *EP, *fcw, *fcb;
    float* out;
    int* tok;
    bf16* h0[2][2];   // [pingpong][hi/lo]
    bf16* h1[2][2];
    unsigned* flags;  // [NBLK] monotonic arrival counters
    unsigned* gen;    // release generation
};

// Grid barrier: each block publishes a monotonic phase flag (release, agent
// scope -> flushes its XCD L2); block 0 gathers with 255 parallel relaxed
// (sc1-coherent) pollers, then releases gen; waiters poll gen relaxed and do
// ONE acquire at the end (single cache-invalidate per barrier, not per poll).
static __device__ __forceinline__ void gbar(unsigned* flags, unsigned* gen,
                                            unsigned ph) {
    __syncthreads();
    const int tid = threadIdx.x;
    if (blockIdx.x == 0) {
        if (tid > 0 && tid < NBLK) {
            while (__hip_atomic_load(flags + tid, __ATOMIC_RELAXED,
                                     __HIP_MEMORY_SCOPE_AGENT) < ph)
                __builtin_amdgcn_s_sleep(1);
        }
        __syncthreads();
        if (tid == 0) {
            __hip_atomic_store(gen, ph, __ATOMIC_RELEASE,
                               __HIP_MEMORY_SCOPE_AGENT);
            (void)__hip_atomic_load(gen, __ATOMIC_ACQUIRE,
                                    __HIP_MEMORY_SCOPE_AGENT);
        }
    } else {
        if (tid == 0) {
            __hip_atomic_store(flags + blockIdx.x, ph, __ATOMIC_RELEASE,
                               __HIP_MEMORY_SCOPE_AGENT);
            while (__hip_atomic_load(gen, __ATOMIC_RELAXED,
                                     __HIP_MEMORY_SCOPE_AGENT) < ph)
                __builtin_amdgcn_s_sleep(1);
            (void)__hip_atomic_load(gen, __ATOMIC_ACQUIRE,
                                    __HIP_MEMORY_SCOPE_AGENT);
        }
    }
    __syncthreads();
}

// layer-1 step phase (encoder L1 and decoder L1), verbatim port of rnn2_step_k
static __device__ __forceinline__ void phase_rnn2(
    const bf16* __restrict__ xhi, const bf16* __restrict__ xlo,
    const bf16* __restrict__ wih, const bf16* __restrict__ wil,
    const bf16* __restrict__ hhi, const bf16* __restrict__ hlo,
    const bf16* __restrict__ whh, const bf16* __restrict__ whl,
    const float* __restrict__ bias,
    bf16* __restrict__ ohi, bf16* __restrict__ olo,
    int mt, int nt, int tile, int role, int lane, int lm, int quad,
    float (*red)[256]) {
    f32x4 acc = (f32x4){0.f, 0.f, 0.f, 0.f};
    if (role == 0) {
        float bv = bias[nt * 16 + lm];
        acc = (f32x4){bv, bv, bv, bv};
        gemm_pipe(xhi + ((size_t)mt * 2048 + lane) * 8,
                  xlo + ((size_t)mt * 2048 + lane) * 8,
                  wih + (size_t)nt * NKB_H * 512 + lane * 8,
                  wil + (size_t)nt * NKB_H * 512 + lane * 8, 0, NKB_H, &acc);
    } else {
        gemm_pipe(hhi + ((size_t)mt * 2048 + lane) * 8,
                  hlo + ((size_t)mt * 2048 + lane) * 8,
                  whh + (size_t)nt * NKB_H * 512 + lane * 8,
                  whl + (size_t)nt * NKB_H * 512 + lane * 8, 0, NKB_H, &acc);
        red[tile][lane * 4 + 0] = acc[0];
        red[tile][lane * 4 + 1] = acc[1];
        red[tile][lane * 4 + 2] = acc[2];
        red[tile][lane * 4 + 3] = acc[3];
    }
    __syncthreads();
    if (role == 0) {
#pragma unroll
        for (int r = 0; r < 4; r++) acc[r] += red[tile][lane * 4 + r];
        store_tile(acc, mt, nt, lm, quad, ohi, olo);
    }
}

__global__ __launch_bounds__(NTHR, 2) void persist_k(Params p) {
    __shared__ union {
        struct { bf16 xh[16 * XST]; bf16 xl[16 * XST]; } xs;  // 31744 B
        double hrow[4][Hh];                                   // 32768 B
    } su;
    __shared__ union {
        float red[4][256];    // 4096 B
        double dred[4][64];   // 2048 B
    } ru;

    const int tid = threadIdx.x;
    const int blk = blockIdx.x;
    const int lane = tid & 63, wave = tid >> 6;
    const int lm = lane & 15, quad = lane >> 4;
    const int tile = wave >> 1, role = wave & 1;   // 4 tiles x 2 roles
    const int mt = blk >> 4;                       // 0..15
    const int nt = (blk & 15) * 4 + tile;          // 0..63
    unsigned ph = 0;

    // ------------------------------ encoder -------------------------------
    for (int t = 0; t < Tt; t++) {
        const int in = t & 1, op = in ^ 1;
        // ---- enc L0 phase (port of enc_step0_k) ----
        {
            for (int idx = tid; idx < 16 * XST; idx += NTHR) {
                int row = idx / XST, col = idx - row * XST;
                float v = (col < LIN)
                    ? p.x[((size_t)(mt * 16 + row) * Tt + t) * LIN + col] : 0.f;
                bf16 h = f2bf(v);
                su.xs.xh[idx] = h;
                su.xs.xl[idx] = f2bf(v - bf2f(h));
            }
            __syncthreads();
            f32x4 acc = (f32x4){0.f, 0.f, 0.f, 0.f};
            const bf16* ah = p.h0[in][0] + ((size_t)mt * 2048 + lane) * 8;
            const bf16* al = p.h0[in][1] + ((size_t)mt * 2048 + lane) * 8;
            const bf16* wha = p.eU0h + (size_t)nt * NKB_H * 512 + lane * 8;
            const bf16* wla = p.eU0l + (size_t)nt * NKB_H * 512 + lane * 8;
            if (role == 0) {
                float bv = p.eb0[nt * 16 + lm];
                acc = (f32x4){bv, bv, bv, bv};
                const bf16* w0h_ = p.w0h + (size_t)nt * NKB_X * 512 + lane * 8;
                const bf16* w0l_ = p.w0l + (size_t)nt * NKB_X * 512 + lane * 8;
                for (int kb = 0; kb < NKB_X; kb++) {
                    bf16x8 a1 = *(const bf16x8*)(&su.xs.xh[lm * XST + kb * 32 + quad * 8]);
                    bf16x8 a2 = *(const bf16x8*)(&su.xs.xl[lm * XST + kb * 32 + quad * 8]);
                    bf16x8 wh8 = *(const bf16x8*)(w0h_ + (size_t)kb * 512);
                    bf16x8 wl8 = *(const bf16x8*)(w0l_ + (size_t)kb * 512);
                    acc = MFMA(a1, wh8, acc);
                    acc = MFMA(a2, wh8, acc);
                    acc = MFMA(a1, wl8, acc);
                }
                gemm_pipe(ah, al, wha, wla, 0, 9, &acc);
            } else {
                gemm_pipe(ah, al, wha, wla, 9, NKB_H, &acc);
                ru.red[tile][lane * 4 + 0] = acc[0];
                ru.red[tile][lane * 4 + 1] = acc[1];
                ru.red[tile][lane * 4 + 2] = acc[2];
                ru.red[tile][lane * 4 + 3] = acc[3];
            }
            __syncthreads();
            if (role == 0) {
#pragma unroll
                for (int r = 0; r < 4; r++) acc[r] += ru.red[tile][lane * 4 + r];
                store_tile(acc, mt, nt, lm, quad, p.h0[op][0], p.h0[op][1]);
            }
        }
        gbar(p.flags, p.gen, ++ph);
        // ---- enc L1 phase ----
        phase_rnn2(p.h0[op][0], p.h0[op][1], p.eW1h, p.eW1l,
                   p.h1[in][0], p.h1[in][1], p.eU1h, p.eU1l, p.eb1,
                   p.h1[op][0], p.h1[op][1],
                   mt, nt, tile, role, lane, lm, quad, ru.red);
        gbar(p.flags, p.gen, ++ph);
    }

    // ------------------------------ decoder -------------------------------
    for (int s = 0; s < ML; s++) {
        const int in = s & 1, op = in ^ 1;
        // ---- dec L0 phase (port of dec_step0_k) ----
        {
            f32x4 acc = (f32x4){0.f, 0.f, 0.f, 0.f};
            const bf16* ah = p.h0[in][0] + ((size_t)mt * 2048 + lane) * 8;
            const bf16* al = p.h0[in][1] + ((size_t)mt * 2048 + lane) * 8;
            const bf16* wha = p.dU0h + (size_t)nt * NKB_H * 512 + lane * 8;
            const bf16* wla = p.dU0l + (size_t)nt * NKB_H * 512 + lane * 8;
            if (role == 0) {
                gemm_pipe(ah, al, wha, wla, 0, 16, &acc);
            } else {
                gemm_pipe(ah, al, wha, wla, 16, NKB_H, &acc);
                ru.red[tile][lane * 4 + 0] = acc[0];
                ru.red[tile][lane * 4 + 1] = acc[1];
                ru.red[tile][lane * 4 + 2] = acc[2];
                ru.red[tile][lane * 4 + 3] = acc[3];
            }
            __syncthreads();
            if (role == 0) {
                const int n = nt * 16 + lm;
#pragma unroll
                for (int r = 0; r < 4; r++) {
                    int tk = p.tok[mt * 16 + quad * 4 + r];
                    acc[r] += ru.red[tile][lane * 4 + r] + p.EP[(size_t)tk * Hh + n];
                }
                store_tile(acc, mt, nt, lm, quad, p.h0[op][0], p.h0[op][1]);
            }
        }
        gbar(p.flags, p.gen, ++ph);
        // ---- dec L1 phase ----
        phase_rnn2(p.h0[op][0], p.h0[op][1], p.dW1h, p.dW1l,
                   p.h1[in][0], p.h1[in][1], p.dU1h, p.dU1l, p.db1,
                   p.h1[op][0], p.h1[op][1],
                   mt, nt, tile, role, lane, lm, quad, ru.red);
        gbar(p.flags, p.gen, ++ph);
        // ---- fc + argmax phase (fp64 token-deciding path) ----
        if (blk < 64) {
            const bf16* h1hi = p.h1[op][0];
            const bf16* h1lo = p.h1[op][1];
            for (int i = tid; i < 4 * Hh; i += NTHR) {
                int r = i >> 10, k = i & 1023;
                int b = blk * 4 + r;
                size_t id = (((size_t)(b >> 4) * 32 + (k >> 5)) * 64
                             + ((k >> 3) & 3) * 16 + (b & 15)) * 8 + (k & 7);
                su.hrow[r][k] = (double)bf2f(h1hi[id]) + (double)bf2f(h1lo[id]);
            }
            __syncthreads();
            const int r = wave >> 1, half = wave & 1;   // 2 waves per batch row
            const int v = lane;
            const int b = blk * 4 + r;
            const float* wr = p.fcw + (size_t)v * Hh;
            double a0 = 0.0, a1 = 0.0, a2 = 0.0, a3 = 0.0;
            const int k0 = half * 512;
            for (int k = k0; k < k0 + 512; k += 4) {
                a0 = fma(su.hrow[r][k + 0], (double)wr[k + 0], a0);
                a1 = fma(su.hrow[r][k + 1], (double)wr[k + 1], a1);
                a2 = fma(su.hrow[r][k + 2], (double)wr[k + 2], a2);
                a3 = fma(su.hrow[r][k + 3], (double)wr[k + 3], a3);
            }
            double part = (a0 + a1) + (a2 + a3);
            if (half == 1) ru.dred[r][v] = part;
            __syncthreads();
            if (half == 0) {
                double acc = part + ru.dred[r][v] + (double)p.fcb[v];
                p.out[(size_t)b * (Vv * ML) + (size_t)v * ML + s] = (float)acc;
                double bvv = acc;
                int bi = v;
#pragma unroll
                for (int st = 1; st < 64; st <<= 1) {
                    double ov = __shfl_xor(bvv, st, 64);
                    int oi = __shfl_xor(bi, st, 64);
                    if (ov > bvv || (ov == bvv && oi < bi)) { bvv = ov; bi = oi; }
                }
                if (v == 0) p.tok[b] = bi;
            }
        }
        gbar(p.flags, p.gen, ++ph);
    }

    // ------------------------ final hidden output -------------------------
    {
        const size_t base = (size_t)Bb * Vv * ML;
        for (int i = blk * NTHR + tid; i < Bb * Hh; i += NBLK * NTHR) {
            const int b = i >> 10, k = i & 1023;
            const size_t idx = (((size_t)(b >> 4) * 32 + (k >> 5)) * 64
                                + ((k >> 3) & 3) * 16 + (b & 15)) * 8 + (k & 7);
            p.out[base + i] = bf2f(p.h0[0][0][idx]) + bf2f(p.h0[0][1][idx]);
            p.out[base + (size_t)Bb * Hh + i] =
                bf2f(p.h1[0][0][idx]) + bf2f(p.h1[0][1][idx]);
        }
    }
}

// ---------------------------------------------------------------------------
extern "C" void kernel_launch(void* const* d_in, const int* in_sizes, int n_in,
                              void* d_out, int out_size, void* d_ws, size_t ws_size,
                              hipStream_t stream) {
    const float* x   = (const float*)d_in[0];
    const float* emb = (const float*)d_in[1];
    const float* eW0 = (const float*)d_in[2];
    const float* eU0 = (const float*)d_in[3];
    const float* eb0 = (const float*)d_in[4];
    const float* eW1 = (const float*)d_in[5];
    const float* eU1 = (const float*)d_in[6];
    const float* eb1 = (const float*)d_in[7];
    const float* dW0 = (const float*)d_in[8];
    const float* dU0 = (const float*)d_in[9];
    const float* db0 = (const float*)d_in[10];
    const float* dW1 = (const float*)d_in[11];
    const float* dU1 = (const float*)d_in[12];
    const float* db1 = (const float*)d_in[13];
    const float* fcw = (const float*)d_in[14];
    const float* fcb = (const float*)d_in[15];
    (void)in_sizes; (void)n_in; (void)out_size; (void)ws_size;

    char* ws = (char*)d_ws;
    const size_t SB = (size_t)Bb * Hh * 2;           // 512 KB state component
    const size_t WPK = (size_t)64 * NKB_H * 512 * 2; // 2 MB packed square comp
    const size_t WPX = (size_t)64 * NKB_X * 512 * 2; // 0.94 MB packed w0 comp
    bf16 *h0c[2][2], *h1c[2][2];
    size_t o = 0;
    for (int c = 0; c < 2; c++) { h0c[0][c] = (bf16*)(ws + o); o += SB; }
    for (int c = 0; c < 2; c++) { h1c[0][c] = (bf16*)(ws + o); o += SB; }
    int* tok = (int*)(ws + o); o += 1024;              // 256 tokens
    unsigned* flags = (unsigned*)(ws + o); o += NBLK * 4;
    unsigned* gen = (unsigned*)(ws + o); o += 256;     // padded, keeps 16B align
    const size_t zero_bytes = o;
    for (int c = 0; c < 2; c++) { h0c[1][c] = (bf16*)(ws + o); o += SB; }
    for (int c = 0; c < 2; c++) { h1c[1][c] = (bf16*)(ws + o); o += SB; }
    float* EP = (float*)(ws + o); o += (size_t)Vv * Hh * 4;
    bf16 *w0p[2];
    for (int c = 0; c < 2; c++) { w0p[c] = (bf16*)(ws + o); o += WPX; }
    bf16 *eU0p[2], *eW1p[2], *eU1p[2], *dU0p[2], *dW1p[2], *dU1p[2];
    for (int c = 0; c < 2; c++) { eU0p[c] = (bf16*)(ws + o); o += WPK; }
    for (int c = 0; c < 2; c++) { eW1p[c] = (bf16*)(ws + o); o += WPK; }
    for (int c = 0; c < 2; c++) { eU1p[c] = (bf16*)(ws + o); o += WPK; }
    for (int c = 0; c < 2; c++) { dU0p[c] = (bf16*)(ws + o); o += WPK; }
    for (int c = 0; c < 2; c++) { dW1p[c] = (bf16*)(ws + o); o += WPK; }
    for (int c = 0; c < 2; c++) { dU1p[c] = (bf16*)(ws + o); o += WPK; }

    hipMemsetAsync(ws, 0, zero_bytes, stream);
    dim3 blk(256);
    const int GSQ = 64 * NKB_H * 64 / 256;   // 512 blocks
    const int GX  = 64 * NKB_X * 64 / 256;   // 240 blocks
    pack_w_k<<<dim3(GX),  blk, 0, stream>>>(eW0, w0p[0],  w0p[1],  NKB_X, LIN, LIN);
    pack_w_k<<<dim3(GSQ), blk, 0, stream>>>(eU0, eU0p[0], eU0p[1], NKB_H, Hh, Hh);
    pack_w_k<<<dim3(GSQ), blk, 0, stream>>>(eW1, eW1p[0], eW1p[1], NKB_H, Hh, Hh);
    pack_w_k<<<dim3(GSQ), blk, 0, stream>>>(eU1, eU1p[0], eU1p[1], NKB_H, Hh, Hh);
    pack_w_k<<<dim3(GSQ), blk, 0, stream>>>(dU0, dU0p[0], dU0p[1], NKB_H, Hh, Hh);
    pack_w_k<<<dim3(GSQ), blk, 0, stream>>>(dW1, dW1p[0], dW1p[1], NKB_H, Hh, Hh);
    pack_w_k<<<dim3(GSQ), blk, 0, stream>>>(dU1, dU1p[0], dU1p[1], NKB_H, Hh, Hh);
    dec_pre_k<<<dim3(Hh / 256, Vv / 4), blk, 0, stream>>>(emb, dW0, db0, EP);

    Params pr;
    pr.x = x;
    pr.w0h = w0p[0];  pr.w0l = w0p[1];
    pr.eU0h = eU0p[0]; pr.eU0l = eU0p[1];
    pr.eW1h = eW1p[0]; pr.eW1l = eW1p[1];
    pr.eU1h = eU1p[0]; pr.eU1l = eU1p[1];
    pr.dU0h = dU0p[0]; pr.dU0l = dU0p[1];
    pr.dW1h = dW1p[0]; pr.dW1l = dW1p[1];
    pr.dU1h = dU1p[0]; pr.dU1l = dU1p[1];
    pr.eb0 = eb0; pr.eb1 = eb1; pr.db1 = db1;
    pr.EP = EP; pr.fcw = fcw; pr.fcb = fcb;
    pr.out = (float*)d_out;
    pr.tok = tok;
    for (int pp = 0; pp < 2; pp++)
        for (int c = 0; c < 2; c++) {
            pr.h0[pp][c] = h0c[pp][c];
            pr.h1[pp][c] = h1c[pp][c];
        }
    pr.flags = flags; pr.gen = gen;

    void* kargs[] = { (void*)&pr };
    hipLaunchCooperativeKernel((void*)persist_k, dim3(NBLK), dim3(NTHR),
                               kargs, 0, stream);
}

// Round 3
// 10494.866 us; speedup vs baseline: 1.2772x; 1.2772x over previous
//
#include <hip/hip_runtime.h>
#include <math.h>

// Trajectory2seq persistent kernel, round 3.
// Round-2 crashed: inline-asm sc0/sc1 loads returned values in VGPRs that
// compiler-scheduled consumers could read BEFORE the separate s_waitcnt asm
// (no HW scoreboard) -> garbage token index -> EP wild load -> HSA abort.
// Round 3 keeps the round-2 architecture (16 independent mt-group barriers
// with relaxed atomics only -> L2 weights stay resident; LDS-staged A panels;
// 2-deep-W-prefetch gemm) but moves ALL coherent traffic to
// __hip_atomic_load/store (RELAXED, AGENT) so the compiler emits the scope
// bits AND the waitcnts. State stores go through an LDS repack so the global
// coherent stores are contiguous u64s. Tokens clamped &63.

#define Bb   256
#define Tt   128
#define Hh   1024
#define Vv   64
#define LIN  457
#define ML   64
#define NKB_H  32   // K=1024 -> 32 k-blocks of 32
#define NKB_X  15   // K=480  -> 15 k-blocks
#define XST  496    // LDS x row stride (bank spread, 16B aligned)
#define NBLK 256    // persistent grid: 1 block per CU
#define NTHR 512    // 8 waves per block

typedef __bf16 bf16;
typedef __bf16 bf16x8 __attribute__((ext_vector_type(8)));
typedef float  f32x4  __attribute__((ext_vector_type(4)));
typedef unsigned long long ull;

static __device__ __forceinline__ float bf2f(bf16 x) {
    unsigned short u = __builtin_bit_cast(unsigned short, x);
    unsigned int w = ((unsigned int)u) << 16;
    return __builtin_bit_cast(float, w);
}
static __device__ __forceinline__ unsigned short f2bfbits(float f) {
    unsigned int u = __builtin_bit_cast(unsigned int, f);
    u = u + 0x7FFFu + ((u >> 16) & 1u);   // RNE (finite only)
    return (unsigned short)(u >> 16);
}
static __device__ __forceinline__ bf16 f2bf(float f) {
    return __builtin_bit_cast(bf16, f2bfbits(f));
}
static __device__ __forceinline__ float ubf(unsigned u) {
    return __builtin_bit_cast(float, u << 16);
}

#define MFMA(a, b, c) __builtin_amdgcn_mfma_f32_16x16x32_bf16((a), (b), (c), 0, 0, 0)

// ---- coherent (agent-scope, LLC) accesses; compiler-managed waitcnts ------
static __device__ __forceinline__ ull ld_c64(const void* p) {
    return __hip_atomic_load((const ull*)p, __ATOMIC_RELAXED,
                             __HIP_MEMORY_SCOPE_AGENT);
}
static __device__ __forceinline__ void st_c64(void* p, ull v) {
    __hip_atomic_store((ull*)p, v, __ATOMIC_RELAXED, __HIP_MEMORY_SCOPE_AGENT);
}
static __device__ __forceinline__ unsigned ld_c32(const void* p) {
    return __hip_atomic_load((const unsigned*)p, __ATOMIC_RELAXED,
                             __HIP_MEMORY_SCOPE_AGENT);
}
static __device__ __forceinline__ void st_c32(void* p, unsigned v) {
    __hip_atomic_store((unsigned*)p, v, __ATOMIC_RELAXED,
                       __HIP_MEMORY_SCOPE_AGENT);
}

// ---- one-time: fp32 W[N][K] -> packed hi/lo fragments ---------------------
__global__ __launch_bounds__(256) void pack_w_k(const float* __restrict__ src,
                                                bf16* __restrict__ hp,
                                                bf16* __restrict__ lp,
                                                int nkb, int src_ld, int kmax) {
    const int tid = blockIdx.x * 256 + threadIdx.x;
    const int lane = tid & 63;
    const int kb = (tid >> 6) % nkb;
    const int nt = tid / (64 * nkb);
    if (nt >= 64) return;
    const int row = nt * 16 + (lane & 15);
    const int k0 = kb * 32 + (lane >> 4) * 8;
    const float* s = src + (size_t)row * src_ld;
    bf16x8 h8, l8;
#pragma unroll
    for (int j = 0; j < 8; j++) {
        float v = (k0 + j < kmax) ? s[k0 + j] : 0.f;
        bf16 h = f2bf(v);
        h8[j] = h;
        l8[j] = f2bf(v - bf2f(h));
    }
    *(bf16x8*)(hp + (size_t)tid * 8) = h8;
    *(bf16x8*)(lp + (size_t)tid * 8) = l8;
}

// ---- 2-deep-W-prefetch 16x16 gemm, A from LDS, split accumulators ---------
template <int ASTR>
static __device__ __forceinline__ void gemm_lds(
    const bf16* aH, const bf16* aL,
    const bf16* __restrict__ wH, const bf16* __restrict__ wL,
    int n, f32x4* accio) {
    f32x4 accA = *accio;
    f32x4 accB = (f32x4){0.f, 0.f, 0.f, 0.f};
    bf16x8 wh0 = *(const bf16x8*)(wH);
    bf16x8 wl0 = *(const bf16x8*)(wL);
    bf16x8 wh1 = wh0, wl1 = wl0;
    if (n > 1) { wh1 = *(const bf16x8*)(wH + 512); wl1 = *(const bf16x8*)(wL + 512); }
    int i = 0;
    for (; i + 2 <= n; i += 2) {
        bf16x8 a0h = *(const bf16x8*)(aH + (size_t)i * ASTR);
        bf16x8 a0l = *(const bf16x8*)(aL + (size_t)i * ASTR);
        bf16x8 a1h = *(const bf16x8*)(aH + (size_t)(i + 1) * ASTR);
        bf16x8 a1l = *(const bf16x8*)(aL + (size_t)(i + 1) * ASTR);
        bf16x8 cwh0 = wh0, cwl0 = wl0, cwh1 = wh1, cwl1 = wl1;
        if (i + 2 < n) { wh0 = *(const bf16x8*)(wH + (size_t)(i + 2) * 512);
                         wl0 = *(const bf16x8*)(wL + (size_t)(i + 2) * 512); }
        if (i + 3 < n) { wh1 = *(const bf16x8*)(wH + (size_t)(i + 3) * 512);
                         wl1 = *(const bf16x8*)(wL + (size_t)(i + 3) * 512); }
        accA = MFMA(a0h, cwh0, accA);
        accA = MFMA(a0l, cwh0, accA);
        accA = MFMA(a0h, cwl0, accA);
        accB = MFMA(a1h, cwh1, accB);
        accB = MFMA(a1l, cwh1, accB);
        accB = MFMA(a1h, cwl1, accB);
    }
    if (i < n) {
        bf16x8 ah_ = *(const bf16x8*)(aH + (size_t)i * ASTR);
        bf16x8 al_ = *(const bf16x8*)(aL + (size_t)i * ASTR);
        accA = MFMA(ah_, wh0, accA);
        accA = MFMA(al_, wh0, accA);
        accA = MFMA(ah_, wl0, accA);
    }
    *accio = accA + accB;
}

// ---- stage one state panel (32KB hi + 32KB lo) into LDS (coherent loads) --
static __device__ __forceinline__ void stage_panel(
    const bf16* gh, const bf16* gl, bf16* sh, bf16* sl, int tid) {
    ull vh[8], vl[8];
#pragma unroll
    for (int j = 0; j < 4; j++) {
        vh[2 * j]     = ld_c64(gh + (size_t)j * 4096 + tid * 8);
        vh[2 * j + 1] = ld_c64(gh + (size_t)j * 4096 + tid * 8 + 4);
        vl[2 * j]     = ld_c64(gl + (size_t)j * 4096 + tid * 8);
        vl[2 * j + 1] = ld_c64(gl + (size_t)j * 4096 + tid * 8 + 4);
    }
#pragma unroll
    for (int j = 0; j < 4; j++) {
        *(ull*)(sh + (size_t)j * 4096 + tid * 8)     = vh[2 * j];
        *(ull*)(sh + (size_t)j * 4096 + tid * 8 + 4) = vh[2 * j + 1];
        *(ull*)(sl + (size_t)j * 4096 + tid * 8)     = vl[2 * j];
        *(ull*)(sl + (size_t)j * 4096 + tid * 8 + 4) = vl[2 * j + 1];
    }
}

// ---- phase output: role0 writes tanh'd hi/lo into LDS stage ---------------
static __device__ __forceinline__ void emit_tile(
    f32x4 acc, bool writer, int tile, int lm, int quad,
    unsigned short* sst_h, unsigned short* sst_l) {
    if (writer) {
        const int base = tile * 256 + (lm >> 3) * 128 + quad * 32 + (lm & 7);
#pragma unroll
        for (int r = 0; r < 4; r++) {
            float h = tanhf(acc[r]);
            unsigned short hb = f2bfbits(h);
            sst_h[base + r * 8] = hb;
            sst_l[base + r * 8] = f2bfbits(h - ubf((unsigned)hb));
        }
    }
    __syncthreads();
}

// ---- all threads: flush 4 tiles (contiguous 256-elem chunks) coherently ---
static __device__ __forceinline__ void flush_tiles(
    const unsigned short* sst_h, const unsigned short* sst_l,
    bf16* ohi, bf16* olo, int mt, int lidx, int tid) {
    const int comp = tid >> 8;           // 0: hi, 1: lo
    const int tile = (tid >> 6) & 3;
    const int q = tid & 63;
    const int nt = lidx * 4 + tile;
    const size_t gb = ((size_t)mt * 32 + (nt >> 1)) * 512
                      + (size_t)(nt & 1) * 256 + q * 4;
    const unsigned short* s = comp ? sst_l : sst_h;
    ull v = *(const ull*)(s + tile * 256 + q * 4);
    st_c64((comp ? olo : ohi) + gb, v);
}

// ------- one-time: EP[v][n] = emb[v] @ dec_Wih0^T + dec_b0 (fp64->fp32) ----
__global__ __launch_bounds__(256) void dec_pre_k(const float* __restrict__ emb,
                                                 const float* __restrict__ W,
                                                 const float* __restrict__ b,
                                                 float* __restrict__ EP) {
    const int n = blockIdx.x * 256 + threadIdx.x;
    const int v = blockIdx.y * 4;
    double acc[4];
    const double bv = (double)b[n];
    acc[0] = acc[1] = acc[2] = acc[3] = bv;
    const float* wr = W + (size_t)n * Hh;
#pragma unroll 4
    for (int k = 0; k < Hh; k++) {
        double wv = (double)wr[k];
        acc[0] = fma((double)emb[(size_t)(v + 0) * Hh + k], wv, acc[0]);
        acc[1] = fma((double)emb[(size_t)(v + 1) * Hh + k], wv, acc[1]);
        acc[2] = fma((double)emb[(size_t)(v + 2) * Hh + k], wv, acc[2]);
        acc[3] = fma((double)emb[(size_t)(v + 3) * Hh + k], wv, acc[3]);
    }
#pragma unroll
    for (int r = 0; r < 4; r++) EP[(size_t)(v + r) * Hh + n] = (float)acc[r];
}

// --------------------------- persistent kernel -----------------------------
struct Params {
    const float* x;
    const bf16 *w0h, *w0l;
    const bf16 *eU0h, *eU0l, *eW1h, *eW1l, *eU1h, *eU1l;
    const bf16 *dU0h, *dU0l, *dW1h, *dW1l, *dU1h, *dU1l;
    const float *eb0, *eb1, *db1;
    const float *EP, *fcw, *fcb;
    float* out;
    int* tok;
    bf16* h0[2][2];   // [pingpong][hi/lo]
    bf16* h1[2][2];
    unsigned* flags;  // [256] monotonic, 128B-strided
};

// group barrier over the 16 blocks of an mt-group: relaxed atomics, no cache
// maintenance. vmcnt(0)+syncthreads orders all prior coherent stores before
// the flag publication.
static __device__ __forceinline__ void gbar16(unsigned* flags, int mt, int lidx,
                                              unsigned ph) {
    asm volatile("s_waitcnt vmcnt(0)" ::: "memory");
    __syncthreads();
    if (threadIdx.x == 0)
        __hip_atomic_store(flags + (size_t)(mt * 16 + lidx) * 32, ph,
                           __ATOMIC_RELAXED, __HIP_MEMORY_SCOPE_AGENT);
    if (threadIdx.x < 16) {
        while (__hip_atomic_load(flags + (size_t)(mt * 16 + threadIdx.x) * 32,
                                 __ATOMIC_RELAXED, __HIP_MEMORY_SCOPE_AGENT) < ph)
            __builtin_amdgcn_s_sleep(1);
    }
    __syncthreads();
    asm volatile("" ::: "memory");
}

static __device__ __forceinline__ size_t sidx(int b, int k) {
    return ((((size_t)(b >> 4)) * 32 + (k >> 5)) * 64 + ((k >> 3) & 3) * 16
            + (b & 15)) * 8 + (k & 7);
}

// layer-1 step (encoder L1 / decoder L1)
static __device__ __forceinline__ void phase_rnn2(
    const bf16* xh_g, const bf16* xl_g,
    const bf16* __restrict__ wih, const bf16* __restrict__ wil,
    const bf16* hh_g, const bf16* hl_g,
    const bf16* __restrict__ whh, const bf16* __restrict__ whl,
    const float* bias, bf16* ohi, bf16* olo,
    bf16* smA_h, bf16* smA_l, bf16* smB_h, bf16* smB_l,
    float* red, unsigned short* sst_h, unsigned short* sst_l,
    int mt, int lidx, int nt, int tile, int role,
    int lane, int lm, int quad, int tid) {
    stage_panel(xh_g + (size_t)mt * 16384, xl_g + (size_t)mt * 16384,
                smA_h, smA_l, tid);
    stage_panel(hh_g + (size_t)mt * 16384, hl_g + (size_t)mt * 16384,
                smB_h, smB_l, tid);
    __syncthreads();
    f32x4 acc = (f32x4){0.f, 0.f, 0.f, 0.f};
    if (role == 0) {
        float bv = bias[nt * 16 + lm];
        acc = (f32x4){bv, bv, bv, bv};
        gemm_lds<512>(smA_h + lane * 8, smA_l + lane * 8,
                      wih + (size_t)nt * NKB_H * 512 + lane * 8,
                      wil + (size_t)nt * NKB_H * 512 + lane * 8, NKB_H, &acc);
    } else {
        gemm_lds<512>(smB_h + lane * 8, smB_l + lane * 8,
                      whh + (size_t)nt * NKB_H * 512 + lane * 8,
                      whl + (size_t)nt * NKB_H * 512 + lane * 8, NKB_H, &acc);
        red[tile * 256 + lane * 4 + 0] = acc[0];
        red[tile * 256 + lane * 4 + 1] = acc[1];
        red[tile * 256 + lane * 4 + 2] = acc[2];
        red[tile * 256 + lane * 4 + 3] = acc[3];
    }
    __syncthreads();
    if (role == 0) {
#pragma unroll
        for (int r = 0; r < 4; r++) acc[r] += red[tile * 256 + lane * 4 + r];
    }
    emit_tile(acc, role == 0, tile, lm, quad, sst_h, sst_l);
    flush_tiles(sst_h, sst_l, ohi, olo, mt, lidx, tid);
}

#define SM_BYTES 139264

__global__ __launch_bounds__(NTHR, 2) void persist_k(Params p) {
    __shared__ __align__(16) char smem[SM_BYTES];
    bf16* const smA_h = (bf16*)smem;                    // 16384 elems (32KB)
    bf16* const smA_l = (bf16*)smem + 16384;
    bf16* const smB_h = (bf16*)smem + 32768;
    bf16* const smB_l = (bf16*)smem + 49152;
    float* const red  = (float*)(smem + 131072);        // 4KB
    unsigned short* const sst_h = (unsigned short*)(smem + 135168);  // 2KB
    unsigned short* const sst_l = (unsigned short*)(smem + 137216);  // 2KB
    double* const hrow = (double*)smem;                 // fc overlay [4][1024]
    double* const dred = (double*)(smem + 131072);      // fc overlay [4][64]
    bf16* const xsh = (bf16*)smem + 32768;              // enc L0 x overlay
    bf16* const xsl = xsh + 16 * XST;

    const int tid = threadIdx.x;
    const int blk = blockIdx.x;
    const int lane = tid & 63, wave = tid >> 6;
    const int lm = lane & 15, quad = lane >> 4;
    const int tile = wave >> 1, role = wave & 1;   // 4 tiles x 2 roles
    const int mt = blk >> 4;                       // group id 0..15
    const int lidx = blk & 15;                     // block-in-group
    const int nt = lidx * 4 + tile;                // 0..63
    unsigned ph = 0;

    // ------------------------------ encoder -------------------------------
    for (int t = 0; t < Tt; t++) {
        const int in = t & 1, op = in ^ 1;
        // ---- enc L0 ----
        {
            for (int idx = tid; idx < 16 * XST; idx += NTHR) {
                int row = idx / XST, col = idx - row * XST;
                float v = 0.f;
                if (col < LIN)
                    v = __builtin_nontemporal_load(
                        &p.x[((size_t)(mt * 16 + row) * Tt + t) * LIN + col]);
                bf16 h = f2bf(v);
                xsh[idx] = h;
                xsl[idx] = f2bf(v - bf2f(h));
            }
            stage_panel(p.h0[in][0] + (size_t)mt * 16384,
                        p.h0[in][1] + (size_t)mt * 16384, smA_h, smA_l, tid);
            __syncthreads();
            f32x4 acc = (f32x4){0.f, 0.f, 0.f, 0.f};
            const bf16* aH = smA_h + lane * 8;
            const bf16* aL = smA_l + lane * 8;
            const bf16* wha = p.eU0h + (size_t)nt * NKB_H * 512 + lane * 8;
            const bf16* wla = p.eU0l + (size_t)nt * NKB_H * 512 + lane * 8;
            if (role == 0) {
                float bv = p.eb0[nt * 16 + lm];
                acc = (f32x4){bv, bv, bv, bv};
                gemm_lds<32>(xsh + lm * XST + quad * 8, xsl + lm * XST + quad * 8,
                             p.w0h + (size_t)nt * NKB_X * 512 + lane * 8,
                             p.w0l + (size_t)nt * NKB_X * 512 + lane * 8,
                             NKB_X, &acc);
                gemm_lds<512>(aH, aL, wha, wla, 9, &acc);
            } else {
                gemm_lds<512>(aH + 9 * 512, aL + 9 * 512, wha + 9 * 512,
                              wla + 9 * 512, 23, &acc);
                red[tile * 256 + lane * 4 + 0] = acc[0];
                red[tile * 256 + lane * 4 + 1] = acc[1];
                red[tile * 256 + lane * 4 + 2] = acc[2];
                red[tile * 256 + lane * 4 + 3] = acc[3];
            }
            __syncthreads();
            if (role == 0) {
#pragma unroll
                for (int r = 0; r < 4; r++) acc[r] += red[tile * 256 + lane * 4 + r];
            }
            emit_tile(acc, role == 0, tile, lm, quad, sst_h, sst_l);
            flush_tiles(sst_h, sst_l, p.h0[op][0], p.h0[op][1], mt, lidx, tid);
        }
        gbar16(p.flags, mt, lidx, ++ph);
        // ---- enc L1 ----
        phase_rnn2(p.h0[op][0], p.h0[op][1], p.eW1h, p.eW1l,
                   p.h1[in][0], p.h1[in][1], p.eU1h, p.eU1l, p.eb1,
                   p.h1[op][0], p.h1[op][1],
                   smA_h, smA_l, smB_h, smB_l, red, sst_h, sst_l,
                   mt, lidx, nt, tile, role, lane, lm, quad, tid);
        gbar16(p.flags, mt, lidx, ++ph);
    }

    // ------------------------------ decoder -------------------------------
    for (int s = 0; s < ML; s++) {
        const int in = s & 1, op = in ^ 1;
        // ---- dec L0 ----
        {
            stage_panel(p.h0[in][0] + (size_t)mt * 16384,
                        p.h0[in][1] + (size_t)mt * 16384, smA_h, smA_l, tid);
            int tk0 = 0, tk1 = 0, tk2 = 0, tk3 = 0;
            if (role == 0) {
                const int* tp = p.tok + mt * 16 + quad * 4;
                tk0 = (int)(ld_c32(tp + 0) & 63u);
                tk1 = (int)(ld_c32(tp + 1) & 63u);
                tk2 = (int)(ld_c32(tp + 2) & 63u);
                tk3 = (int)(ld_c32(tp + 3) & 63u);
            }
            __syncthreads();
            f32x4 acc = (f32x4){0.f, 0.f, 0.f, 0.f};
            const bf16* aH = smA_h + lane * 8;
            const bf16* aL = smA_l + lane * 8;
            const bf16* wha = p.dU0h + (size_t)nt * NKB_H * 512 + lane * 8;
            const bf16* wla = p.dU0l + (size_t)nt * NKB_H * 512 + lane * 8;
            if (role == 0) {
                gemm_lds<512>(aH, aL, wha, wla, 16, &acc);
            } else {
                gemm_lds<512>(aH + 16 * 512, aL + 16 * 512, wha + 16 * 512,
                              wla + 16 * 512, 16, &acc);
                red[tile * 256 + lane * 4 + 0] = acc[0];
                red[tile * 256 + lane * 4 + 1] = acc[1];
                red[tile * 256 + lane * 4 + 2] = acc[2];
                red[tile * 256 + lane * 4 + 3] = acc[3];
            }
            __syncthreads();
            if (role == 0) {
                const int n = nt * 16 + lm;
                acc[0] += red[tile * 256 + lane * 4 + 0] + p.EP[(size_t)tk0 * Hh + n];
                acc[1] += red[tile * 256 + lane * 4 + 1] + p.EP[(size_t)tk1 * Hh + n];
                acc[2] += red[tile * 256 + lane * 4 + 2] + p.EP[(size_t)tk2 * Hh + n];
                acc[3] += red[tile * 256 + lane * 4 + 3] + p.EP[(size_t)tk3 * Hh + n];
            }
            emit_tile(acc, role == 0, tile, lm, quad, sst_h, sst_l);
            flush_tiles(sst_h, sst_l, p.h0[op][0], p.h0[op][1], mt, lidx, tid);
        }
        gbar16(p.flags, mt, lidx, ++ph);
        // ---- dec L1 ----
        phase_rnn2(p.h0[op][0], p.h0[op][1], p.dW1h, p.dW1l,
                   p.h1[in][0], p.h1[in][1], p.dU1h, p.dU1l, p.db1,
                   p.h1[op][0], p.h1[op][1],
                   smA_h, smA_l, smB_h, smB_l, red, sst_h, sst_l,
                   mt, lidx, nt, tile, role, lane, lm, quad, tid);
        gbar16(p.flags, mt, lidx, ++ph);
        // ---- fc + argmax (blocks lidx 0..3 of each group; fp64 path) ----
        if (lidx < 4) {
            const bf16* h1hi = p.h1[op][0];
            const bf16* h1lo = p.h1[op][1];
            {
                const int r = tid >> 7, k8 = tid & 127;
                const int b = mt * 16 + lidx * 4 + r;
                const size_t id = (((size_t)mt * 32 + (k8 >> 2)) * 64
                                   + (k8 & 3) * 16 + (b & 15)) * 8;
                ull h0v = ld_c64(h1hi + id);
                ull h1v = ld_c64(h1hi + id + 4);
                ull l0v = ld_c64(h1lo + id);
                ull l1v = ld_c64(h1lo + id + 4);
#pragma unroll
                for (int j = 0; j < 4; j++) {
                    hrow[r * 1024 + k8 * 8 + j] =
                        (double)ubf((unsigned)((h0v >> (16 * j)) & 0xffffu))
                      + (double)ubf((unsigned)((l0v >> (16 * j)) & 0xffffu));
                    hrow[r * 1024 + k8 * 8 + 4 + j] =
                        (double)ubf((unsigned)((h1v >> (16 * j)) & 0xffffu))
                      + (double)ubf((unsigned)((l1v >> (16 * j)) & 0xffffu));
                }
            }
            __syncthreads();
            const int r2 = wave >> 1, half = wave & 1, v = lane;
            const int b2 = mt * 16 + lidx * 4 + r2;
            const double* hr = hrow + r2 * 1024 + half * 512;
            const float* wrh = p.fcw + (size_t)v * Hh + half * 512;
            double a0 = 0.0, a1 = 0.0, a2 = 0.0, a3 = 0.0;
            for (int k = 0; k < 512; k += 4) {
                a0 = fma(hr[k + 0], (double)wrh[k + 0], a0);
                a1 = fma(hr[k + 1], (double)wrh[k + 1], a1);
                a2 = fma(hr[k + 2], (double)wrh[k + 2], a2);
                a3 = fma(hr[k + 3], (double)wrh[k + 3], a3);
            }
            double part = (a0 + a1) + (a2 + a3);
            if (half == 1) dred[r2 * 64 + v] = part;
            __syncthreads();
            if (half == 0) {
                double acc = part + dred[r2 * 64 + v] + (double)p.fcb[v];
                p.out[(size_t)b2 * (Vv * ML) + (size_t)v * ML + s] = (float)acc;
                double bvv = acc;
                int bi = v;
#pragma unroll
                for (int st = 1; st < 64; st <<= 1) {
                    double ov = __shfl_xor(bvv, st, 64);
                    int oi = __shfl_xor(bi, st, 64);
                    if (ov > bvv || (ov == bvv && oi < bi)) { bvv = ov; bi = oi; }
                }
                if (v == 0) st_c32(p.tok + b2, (unsigned)bi);
            }
        }
        gbar16(p.flags, mt, lidx, ++ph);
    }

    // ------------- final hidden output (group-local rows) ------------------
    {
        const size_t base = (size_t)Bb * Vv * ML;
        const int b = mt * 16 + lidx;
        const int layer = tid >> 8;          // 0: h0, 1: h1
        const int k0 = (tid & 255) * 4;
        const bf16* ph_ = layer ? p.h1[0][0] : p.h0[0][0];
        const bf16* pl_ = layer ? p.h1[0][1] : p.h0[0][1];
        const size_t id = sidx(b, k0);
        ull vh = ld_c64(ph_ + id);
        ull vl = ld_c64(pl_ + id);
        float* o = p.out + base + (size_t)layer * Bb * Hh + (size_t)b * Hh + k0;
#pragma unroll
        for (int j = 0; j < 4; j++)
            o[j] = ubf((unsigned)((vh >> (16 * j)) & 0xffffu))
                 + ubf((unsigned)((vl >> (16 * j)) & 0xffffu));
    }
}

// ---------------------------------------------------------------------------
extern "C" void kernel_launch(void* const* d_in, const int* in_sizes, int n_in,
                              void* d_out, int out_size, void* d_ws, size_t ws_size,
                              hipStream_t stream) {
    const float* x   = (const float*)d_in[0];
    const float* emb = (const float*)d_in[1];
    const float* eW0 = (const float*)d_in[2];
    const float* eU0 = (const float*)d_in[3];
    const float* eb0 = (const float*)d_in[4];
    const float* eW1 = (const float*)d_in[5];
    const float* eU1 = (const float*)d_in[6];
    const float* eb1 = (const float*)d_in[7];
    const float* dW0 = (const float*)d_in[8];
    const float* dU0 = (const float*)d_in[9];
    const float* db0 = (const float*)d_in[10];
    const float* dW1 = (const float*)d_in[11];
    const float* dU1 = (const float*)d_in[12];
    const float* db1 = (const float*)d_in[13];
    const float* fcw = (const float*)d_in[14];
    const float* fcb = (const float*)d_in[15];
    (void)in_sizes; (void)n_in; (void)out_size; (void)ws_size;

    char* ws = (char*)d_ws;
    const size_t SB = (size_t)Bb * Hh * 2;           // 512 KB state component
    const size_t WPK = (size_t)64 * NKB_H * 512 * 2; // 2 MB packed square comp
    const size_t WPX = (size_t)64 * NKB_X * 512 * 2; // 0.94 MB packed w0 comp
    bf16 *h0c[2][2], *h1c[2][2];
    size_t o = 0;
    for (int c = 0; c < 2; c++) { h0c[0][c] = (bf16*)(ws + o); o += SB; }
    for (int c = 0; c < 2; c++) { h1c[0][c] = (bf16*)(ws + o); o += SB; }
    int* tok = (int*)(ws + o); o += 1024;              // 256 tokens
    unsigned* flags = (unsigned*)(ws + o); o += 256 * 128;  // 128B-strided
    const size_t zero_bytes = o;
    for (int c = 0; c < 2; c++) { h0c[1][c] = (bf16*)(ws + o); o += SB; }
    for (int c = 0; c < 2; c++) { h1c[1][c] = (bf16*)(ws + o); o += SB; }
    float* EP = (float*)(ws + o); o += (size_t)Vv * Hh * 4;
    bf16 *w0p[2];
    for (int c = 0; c < 2; c++) { w0p[c] = (bf16*)(ws + o); o += WPX; }
    bf16 *eU0p[2], *eW1p[2], *eU1p[2], *dU0p[2], *dW1p[2], *dU1p[2];
    for (int c = 0; c < 2; c++) { eU0p[c] = (bf16*)(ws + o); o += WPK; }
    for (int c = 0; c < 2; c++) { eW1p[c] = (bf16*)(ws + o); o += WPK; }
    for (int c = 0; c < 2; c++) { eU1p[c] = (bf16*)(ws + o); o += WPK; }
    for (int c = 0; c < 2; c++) { dU0p[c] = (bf16*)(ws + o); o += WPK; }
    for (int c = 0; c < 2; c++) { dW1p[c] = (bf16*)(ws + o); o += WPK; }
    for (int c = 0; c < 2; c++) { dU1p[c] = (bf16*)(ws + o); o += WPK; }

    hipMemsetAsync(ws, 0, zero_bytes, stream);
    dim3 blk(256);
    const int GSQ = 64 * NKB_H * 64 / 256;   // 512 blocks
    const int GX  = 64 * NKB_X * 64 / 256;   // 240 blocks
    pack_w_k<<<dim3(GX),  blk, 0, stream>>>(eW0, w0p[0],  w0p[1],  NKB_X, LIN, LIN);
    pack_w_k<<<dim3(GSQ), blk, 0, stream>>>(eU0, eU0p[0], eU0p[1], NKB_H, Hh, Hh);
    pack_w_k<<<dim3(GSQ), blk, 0, stream>>>(eW1, eW1p[0], eW1p[1], NKB_H, Hh, Hh);
    pack_w_k<<<dim3(GSQ), blk, 0, stream>>>(eU1, eU1p[0], eU1p[1], NKB_H, Hh, Hh);
    pack_w_k<<<dim3(GSQ), blk, 0, stream>>>(dU0, dU0p[0], dU0p[1], NKB_H, Hh, Hh);
    pack_w_k<<<dim3(GSQ), blk, 0, stream>>>(dW1, dW1p[0], dW1p[1], NKB_H, Hh, Hh);
    pack_w_k<<<dim3(GSQ), blk, 0, stream>>>(dU1, dU1p[0], dU1p[1], NKB_H, Hh, Hh);
    dec_pre_k<<<dim3(Hh / 256, Vv / 4), blk, 0, stream>>>(emb, dW0, db0, EP);

    Params pr;
    pr.x = x;
    pr.w0h = w0p[0];  pr.w0l = w0p[1];
    pr.eU0h = eU0p[0]; pr.eU0l = eU0p[1];
    pr.eW1h = eW1p[0]; pr.eW1l = eW1p[1];
    pr.eU1h = eU1p[0]; pr.eU1l = eU1p[1];
    pr.dU0h = dU0p[0]; pr.dU0l = dU0p[1];
    pr.dW1h = dW1p[0]; pr.dW1l = dW1p[1];
    pr.dU1h = dU1p[0]; pr.dU1l = dU1p[1];
    pr.eb0 = eb0; pr.eb1 = eb1; pr.db1 = db1;
    pr.EP = EP; pr.fcw = fcw; pr.fcb = fcb;
    pr.out = (float*)d_out;
    pr.tok = tok;
    for (int pp = 0; pp < 2; pp++)
        for (int c = 0; c < 2; c++) {
            pr.h0[pp][c] = h0c[pp][c];
            pr.h1[pp][c] = h1c[pp][c];
        }
    pr.flags = flags;

    void* kargs[] = { (void*)&pr };
    hipLaunchCooperativeKernel((void*)persist_k, dim3(NBLK), dim3(NTHR),
                               kargs, 0, stream);
}